// Round 1
// baseline (671.959 us; speedup 1.0000x reference)
//
#include <hip/hip_runtime.h>

#define NEG_SLOPE 0.2f

__device__ __forceinline__ float leaky(float x) { return x > 0.f ? x : NEG_SLOPE * x; }

// ---------------- CSR build (dst -> incoming srcs), shared by both layers ----------------
__global__ void k_count(const int* __restrict__ dst, int E, int* __restrict__ cnt) {
    int i = blockIdx.x * blockDim.x + threadIdx.x;
    if (i < E) atomicAdd(&cnt[dst[i]], 1);
}

__global__ void k_scan(const int* __restrict__ cnt, int* __restrict__ rowptr, int n) {
    __shared__ int buf[1024];
    __shared__ int carry_s;
    if (threadIdx.x == 0) { carry_s = 0; rowptr[0] = 0; }
    __syncthreads();
    for (int base = 0; base < n; base += 1024) {
        int i = base + threadIdx.x;
        int v = (i < n) ? cnt[i] : 0;
        buf[threadIdx.x] = v;
        __syncthreads();
        for (int off = 1; off < 1024; off <<= 1) {
            int t = (threadIdx.x >= off) ? buf[threadIdx.x - off] : 0;
            __syncthreads();
            buf[threadIdx.x] += t;
            __syncthreads();
        }
        int incl = buf[threadIdx.x] + carry_s;
        if (i < n) rowptr[i + 1] = incl;
        __syncthreads();
        if (threadIdx.x == 1023) carry_s = incl;
        __syncthreads();
    }
}

__global__ void k_copy(const int* __restrict__ src, int* __restrict__ dst, int n) {
    int i = blockIdx.x * blockDim.x + threadIdx.x;
    if (i < n) dst[i] = src[i];
}

__global__ void k_scatter(const int* __restrict__ srcn, const int* __restrict__ dstn, int E,
                          int* __restrict__ wptr, int* __restrict__ col) {
    int i = blockIdx.x * blockDim.x + threadIdx.x;
    if (i < E) {
        int d = dstn[i];
        int pos = atomicAdd(&wptr[d], 1);
        col[pos] = srcn[i];
    }
}

// ---------------- generic tiled fp32 GEMM: C[M,N] = A[M,K] @ B[K,N] ----------------
// BM=64, BN=64, BK=32; 256 threads, 4x4 micro-tile. N multiple of 64, K multiple of 32.
__global__ __launch_bounds__(256) void k_gemm(const float* __restrict__ A, const float* __restrict__ B,
                                              float* __restrict__ C, int M, int N, int K) {
    __shared__ float As[64][33];
    __shared__ float Bs[32][64];
    int row0 = blockIdx.x * 64, col0 = blockIdx.y * 64;
    int tid = threadIdx.x;
    int tx = tid % 16, ty = tid / 16;
    float acc[4][4] = {};
    for (int kk = 0; kk < K; kk += 32) {
        {
            int r = tid / 8, c4 = tid % 8;
            #pragma unroll
            for (int rr = r; rr < 64; rr += 32) {
                int gr = row0 + rr;
                float4 v = make_float4(0.f, 0.f, 0.f, 0.f);
                if (gr < M) v = *reinterpret_cast<const float4*>(&A[(size_t)gr * K + kk + c4 * 4]);
                As[rr][c4 * 4 + 0] = v.x; As[rr][c4 * 4 + 1] = v.y;
                As[rr][c4 * 4 + 2] = v.z; As[rr][c4 * 4 + 3] = v.w;
            }
            int r2 = tid / 16, c42 = tid % 16;
            #pragma unroll
            for (int rr = r2; rr < 32; rr += 16) {
                float4 v = *reinterpret_cast<const float4*>(&B[(size_t)(kk + rr) * N + col0 + c42 * 4]);
                *reinterpret_cast<float4*>(&Bs[rr][c42 * 4]) = v;
            }
        }
        __syncthreads();
        #pragma unroll
        for (int k = 0; k < 32; k++) {
            float a[4], b[4];
            #pragma unroll
            for (int i = 0; i < 4; i++) a[i] = As[ty * 4 + i][k];
            #pragma unroll
            for (int j = 0; j < 4; j++) b[j] = Bs[k][tx * 4 + j];
            #pragma unroll
            for (int i = 0; i < 4; i++)
                #pragma unroll
                for (int j = 0; j < 4; j++) acc[i][j] = fmaf(a[i], b[j], acc[i][j]);
        }
        __syncthreads();
    }
    #pragma unroll
    for (int i = 0; i < 4; i++) {
        int gr = row0 + ty * 4 + i;
        if (gr < M) {
            float4 v = make_float4(acc[i][0], acc[i][1], acc[i][2], acc[i][3]);
            *reinterpret_cast<float4*>(&C[(size_t)gr * N + col0 + tx * 4]) = v;
        }
    }
}

// ---------------- per-node attention coefficients ----------------
// layer1: h [n,256] (4 heads x 64), a_s/a_d [256] -> asrc/adst [n,4]
__global__ __launch_bounds__(256) void k_alpha1(const float* __restrict__ h,
                                                const float* __restrict__ a_s, const float* __restrict__ a_d,
                                                float* __restrict__ asrc, float* __restrict__ adst, int n) {
    int node = blockIdx.x;
    int t = threadIdx.x, hd = t >> 6, lane = t & 63;
    float v = h[(size_t)node * 256 + t];
    float ps = v * a_s[t], pd = v * a_d[t];
    #pragma unroll
    for (int off = 32; off; off >>= 1) { ps += __shfl_xor(ps, off); pd += __shfl_xor(pd, off); }
    if (lane == 0) { asrc[node * 4 + hd] = ps; adst[node * 4 + hd] = pd; }
}

// layer2: h [n,64], a_s/a_d [64] -> asrc/adst [n]
__global__ __launch_bounds__(256) void k_alpha2(const float* __restrict__ h,
                                                const float* __restrict__ a_s, const float* __restrict__ a_d,
                                                float* __restrict__ asrc, float* __restrict__ adst, int n) {
    int node = blockIdx.x * 4 + (threadIdx.x >> 6);
    int lane = threadIdx.x & 63;
    if (node >= n) return;
    float v = h[(size_t)node * 64 + lane];
    float ps = v * a_s[lane], pd = v * a_d[lane];
    #pragma unroll
    for (int off = 32; off; off >>= 1) { ps += __shfl_xor(ps, off); pd += __shfl_xor(pd, off); }
    if (lane == 0) { asrc[node] = ps; adst[node] = pd; }
}

// ---------------- attention aggregation ----------------
// layer1: block = 1 node, wave w = head w; lane = channel. out = relu(agg/denom + bias)
__global__ __launch_bounds__(256) void k_agg1(const float* __restrict__ h, const float* __restrict__ asrc,
                                              const float* __restrict__ adst, const int* __restrict__ rowptr,
                                              const int* __restrict__ col, const float* __restrict__ bias,
                                              float* __restrict__ out, int n) {
    int node = blockIdx.x;
    int hd = threadIdx.x >> 6, lane = threadIdx.x & 63;
    int base = rowptr[node], deg = rowptr[node + 1] - base;
    float adst_n = adst[node * 4 + hd];
    float e_self = leaky(asrc[node * 4 + hd] + adst_n);
    float m = e_self;
    for (int i = lane; i < deg; i += 64) {
        int s = col[base + i];
        m = fmaxf(m, leaky(asrc[s * 4 + hd] + adst_n));
    }
    #pragma unroll
    for (int off = 32; off; off >>= 1) m = fmaxf(m, __shfl_xor(m, off));
    float p_self = __expf(e_self - m);
    float denom = (lane == 0) ? p_self : 0.f;
    float acc = p_self * h[(size_t)node * 256 + hd * 64 + lane];
    for (int c0 = 0; c0 < deg; c0 += 64) {
        int i = c0 + lane;
        float p = 0.f; int s = 0;
        if (i < deg) {
            s = col[base + i];
            p = __expf(leaky(asrc[s * 4 + hd] + adst_n) - m);
        }
        denom += p;
        int cntE = min(64, deg - c0);
        for (int j = 0; j < cntE; j++) {
            int sj = __shfl(s, j);
            float pj = __shfl(p, j);
            acc = fmaf(pj, h[(size_t)sj * 256 + hd * 64 + lane], acc);
        }
    }
    #pragma unroll
    for (int off = 32; off; off >>= 1) denom += __shfl_xor(denom, off);
    float r = acc / (denom + 1e-16f) + bias[hd * 64 + lane];
    out[(size_t)node * 256 + hd * 64 + lane] = fmaxf(r, 0.f);
}

// layer2: wave = 1 node (1 head), lane = channel
__global__ __launch_bounds__(256) void k_agg2(const float* __restrict__ h, const float* __restrict__ asrc,
                                              const float* __restrict__ adst, const int* __restrict__ rowptr,
                                              const int* __restrict__ col, const float* __restrict__ bias,
                                              float* __restrict__ out, int n) {
    int node = blockIdx.x * 4 + (threadIdx.x >> 6);
    int lane = threadIdx.x & 63;
    if (node >= n) return;
    int base = rowptr[node], deg = rowptr[node + 1] - base;
    float adst_n = adst[node];
    float e_self = leaky(asrc[node] + adst_n);
    float m = e_self;
    for (int i = lane; i < deg; i += 64) {
        int s = col[base + i];
        m = fmaxf(m, leaky(asrc[s] + adst_n));
    }
    #pragma unroll
    for (int off = 32; off; off >>= 1) m = fmaxf(m, __shfl_xor(m, off));
    float p_self = __expf(e_self - m);
    float denom = (lane == 0) ? p_self : 0.f;
    float acc = p_self * h[(size_t)node * 64 + lane];
    for (int c0 = 0; c0 < deg; c0 += 64) {
        int i = c0 + lane;
        float p = 0.f; int s = 0;
        if (i < deg) {
            s = col[base + i];
            p = __expf(leaky(asrc[s] + adst_n) - m);
        }
        denom += p;
        int cntE = min(64, deg - c0);
        for (int j = 0; j < cntE; j++) {
            int sj = __shfl(s, j);
            float pj = __shfl(p, j);
            acc = fmaf(pj, h[(size_t)sj * 64 + lane], acc);
        }
    }
    #pragma unroll
    for (int off = 32; off; off >>= 1) denom += __shfl_xor(denom, off);
    float r = acc / (denom + 1e-16f) + bias[lane];
    out[(size_t)node * 64 + lane] = fmaxf(r, 0.f);
}

// ---------------- final FC: out[n,5] = h[n,64] @ Wfc[64,5] + bfc ----------------
__global__ __launch_bounds__(256) void k_fc(const float* __restrict__ h, const float* __restrict__ W,
                                            const float* __restrict__ b, float* __restrict__ out, int n) {
    int node = blockIdx.x * 4 + (threadIdx.x >> 6);
    int lane = threadIdx.x & 63;
    if (node >= n) return;
    float v = h[(size_t)node * 64 + lane];
    #pragma unroll
    for (int a = 0; a < 5; a++) {
        float part = v * W[lane * 5 + a];
        #pragma unroll
        for (int off = 32; off; off >>= 1) part += __shfl_xor(part, off);
        if (lane == 0) out[(size_t)node * 5 + a] = part + b[a];
    }
}

extern "C" void kernel_launch(void* const* d_in, const int* in_sizes, int n_in,
                              void* d_out, int out_size, void* d_ws, size_t ws_size,
                              hipStream_t stream) {
    const float* x   = (const float*)d_in[0];
    const int*   ei  = (const int*)d_in[1];
    const float* W1  = (const float*)d_in[2];
    const float* a1s = (const float*)d_in[3];
    const float* a1d = (const float*)d_in[4];
    const float* b1  = (const float*)d_in[5];
    const float* W2  = (const float*)d_in[6];
    const float* a2s = (const float*)d_in[7];
    const float* a2d = (const float*)d_in[8];
    const float* b2  = (const float*)d_in[9];
    const float* Wfc = (const float*)d_in[10];
    const float* bfc = (const float*)d_in[11];
    float* out = (float*)d_out;

    int n = in_sizes[0] / 128;
    int E = in_sizes[1] / 2;
    const int* srcn = ei;
    const int* dstn = ei + E;

    char* ws = (char*)d_ws;
    size_t off = 0;
    auto alloc = [&](size_t bytes) -> void* {
        void* p = ws + off;
        off += (bytes + 255) & ~(size_t)255;
        return p;
    };
    float* h1    = (float*)alloc((size_t)n * 256 * 4);
    float* out1  = (float*)alloc((size_t)n * 256 * 4);
    float* asrc1 = (float*)alloc((size_t)n * 4 * 4);
    float* adst1 = (float*)alloc((size_t)n * 4 * 4);
    int*   rowptr = (int*)alloc((size_t)(n + 1) * 4);
    int*   wptr   = (int*)alloc((size_t)n * 4);
    int*   col    = (int*)alloc((size_t)E * 4);
    // aliases for layer-2 (layer-1 buffers dead by then)
    float* h2    = h1;
    float* out2  = out1;
    float* asrc2 = asrc1;
    float* adst2 = adst1;

    // ---- CSR build (once; graph shared by both layers) ----
    hipMemsetAsync(wptr, 0, (size_t)n * 4, stream);
    k_count<<<(E + 255) / 256, 256, 0, stream>>>(dstn, E, wptr);
    k_scan<<<1, 1024, 0, stream>>>(wptr, rowptr, n);
    k_copy<<<(n + 255) / 256, 256, 0, stream>>>(rowptr, wptr, n);
    k_scatter<<<(E + 255) / 256, 256, 0, stream>>>(srcn, dstn, E, wptr, col);

    int mtiles = (n + 63) / 64;
    // ---- layer 1 ----
    k_gemm<<<dim3(mtiles, 4), 256, 0, stream>>>(x, W1, h1, n, 256, 128);
    k_alpha1<<<n, 256, 0, stream>>>(h1, a1s, a1d, asrc1, adst1, n);
    k_agg1<<<n, 256, 0, stream>>>(h1, asrc1, adst1, rowptr, col, b1, out1, n);
    // ---- layer 2 ----
    k_gemm<<<dim3(mtiles, 1), 256, 0, stream>>>(out1, W2, h2, n, 64, 256);
    k_alpha2<<<(n + 3) / 4, 256, 0, stream>>>(h2, a2s, a2d, asrc2, adst2, n);
    k_agg2<<<(n + 3) / 4, 256, 0, stream>>>(h2, asrc2, adst2, rowptr, col, b2, out2, n);
    // ---- FC ----
    k_fc<<<(n + 3) / 4, 256, 0, stream>>>(out2, Wfc, bfc, out, n);
}

// Round 2
// 546.517 us; speedup vs baseline: 1.2295x; 1.2295x over previous
//
#include <hip/hip_runtime.h>

#define NEG_SLOPE 0.2f

__device__ __forceinline__ float leaky(float x) { return x > 0.f ? x : NEG_SLOPE * x; }

// ---------------- CSR build (dst -> incoming srcs), shared by both layers ----------------
__global__ void k_count(const int* __restrict__ dst, int E, int* __restrict__ cnt) {
    int i = blockIdx.x * blockDim.x + threadIdx.x;
    if (i < E) atomicAdd(&cnt[dst[i]], 1);
}

// hierarchical scan: A) per-block (1024 elems) local scan + block sums
__global__ __launch_bounds__(256) void k_scanA(const int* __restrict__ cnt, int* __restrict__ rowptr,
                                               int* __restrict__ bsum, int n) {
    int b = blockIdx.x, t = threadIdx.x;
    int lane = t & 63, w = t >> 6;
    int i0 = b * 1024 + t * 4;
    int v0 = (i0 + 0 < n) ? cnt[i0 + 0] : 0;
    int v1 = (i0 + 1 < n) ? cnt[i0 + 1] : 0;
    int v2 = (i0 + 2 < n) ? cnt[i0 + 2] : 0;
    int v3 = (i0 + 3 < n) ? cnt[i0 + 3] : 0;
    int r0 = v0, r1 = r0 + v1, r2 = r1 + v2, r3 = r2 + v3;
    int s = r3;
    // wave-inclusive scan of thread totals
    int q = s;
    #pragma unroll
    for (int off = 1; off < 64; off <<= 1) {
        int tval = __shfl_up(q, off);
        if (lane >= off) q += tval;
    }
    __shared__ int wsum[4];
    if (lane == 63) wsum[w] = q;
    __syncthreads();
    int woff = 0;
    #pragma unroll
    for (int k = 0; k < 4; k++) if (k < w) woff += wsum[k];
    int excl = woff + q - s;  // exclusive prefix for this thread within block
    if (i0 + 0 < n) rowptr[1 + i0 + 0] = excl + r0;
    if (i0 + 1 < n) rowptr[1 + i0 + 1] = excl + r1;
    if (i0 + 2 < n) rowptr[1 + i0 + 2] = excl + r2;
    if (i0 + 3 < n) rowptr[1 + i0 + 3] = excl + r3;
    if (t == 255) bsum[b] = woff + q;
}

// B) scan block sums (nb <= 64, single wave)
__global__ void k_scanB(const int* __restrict__ bsum, int* __restrict__ bscan, int nb) {
    int lane = threadIdx.x & 63;
    int v = (lane < nb) ? bsum[lane] : 0;
    #pragma unroll
    for (int off = 1; off < 64; off <<= 1) {
        int t = __shfl_up(v, off);
        if (lane >= off) v += t;
    }
    if (lane < nb) bscan[lane] = v;
}

// C) add scanned block offsets
__global__ __launch_bounds__(256) void k_scanC(int* __restrict__ rowptr, const int* __restrict__ bscan, int n) {
    int b = blockIdx.x, t = threadIdx.x;
    int i0 = b * 1024 + t * 4;
    if (b == 0) {
        if (t == 0) rowptr[0] = 0;
        return;
    }
    int add = bscan[b - 1];
    #pragma unroll
    for (int j = 0; j < 4; j++)
        if (i0 + j < n) rowptr[1 + i0 + j] += add;
}

__global__ void k_copy(const int* __restrict__ src, int* __restrict__ dst, int n) {
    int i = blockIdx.x * blockDim.x + threadIdx.x;
    if (i < n) dst[i] = src[i];
}

__global__ void k_scatter(const int* __restrict__ srcn, const int* __restrict__ dstn, int E,
                          int* __restrict__ wptr, int* __restrict__ col) {
    int i = blockIdx.x * blockDim.x + threadIdx.x;
    if (i < E) {
        int d = dstn[i];
        int pos = atomicAdd(&wptr[d], 1);
        col[pos] = srcn[i];
    }
}

// ---------------- tiled fp32 GEMM: C[M,N] = A[M,K] @ B[K,N] ----------------
// BMT in {64,128}; BN=64, BK=32; 256 threads; microtile (BMT/16) x 4.
template <int BMT>
__global__ __launch_bounds__(256) void k_gemm(const float* __restrict__ A, const float* __restrict__ B,
                                              float* __restrict__ C, int M, int N, int K) {
    constexpr int RT = BMT / 16;       // rows per thread
    constexpr int APASS = BMT / 32;    // A-load passes
    __shared__ float As[32][BMT + 4];  // k-major (transposed)
    __shared__ float Bs[32][68];
    int row0 = blockIdx.x * BMT, col0 = blockIdx.y * 64;
    int tid = threadIdx.x;
    int tx = tid & 15, ty = tid >> 4;
    float acc[RT][4] = {};
    for (int kk = 0; kk < K; kk += 32) {
        int ar = tid >> 3;
        int ac = (tid & 7) * 4;
        #pragma unroll
        for (int p = 0; p < APASS; p++) {
            int r = ar + p * 32;
            int gr = row0 + r;
            float4 v = make_float4(0.f, 0.f, 0.f, 0.f);
            if (gr < M) v = *reinterpret_cast<const float4*>(&A[(size_t)gr * K + kk + ac]);
            As[ac + 0][r] = v.x; As[ac + 1][r] = v.y;
            As[ac + 2][r] = v.z; As[ac + 3][r] = v.w;
        }
        int br = tid >> 4;
        int bc = (tid & 15) * 4;
        #pragma unroll
        for (int p = 0; p < 2; p++) {
            int r = br + p * 16;
            float4 v = *reinterpret_cast<const float4*>(&B[(size_t)(kk + r) * N + col0 + bc]);
            *reinterpret_cast<float4*>(&Bs[r][bc]) = v;
        }
        __syncthreads();
        #pragma unroll
        for (int k = 0; k < 32; k++) {
            float a[RT];
            #pragma unroll
            for (int i = 0; i < RT; i += 4) {
                float4 av = *reinterpret_cast<const float4*>(&As[k][ty * RT + i]);
                a[i + 0] = av.x; a[i + 1] = av.y; a[i + 2] = av.z; a[i + 3] = av.w;
            }
            float4 bv = *reinterpret_cast<const float4*>(&Bs[k][tx * 4]);
            float b[4] = {bv.x, bv.y, bv.z, bv.w};
            #pragma unroll
            for (int i = 0; i < RT; i++)
                #pragma unroll
                for (int j = 0; j < 4; j++) acc[i][j] = fmaf(a[i], b[j], acc[i][j]);
        }
        __syncthreads();
    }
    #pragma unroll
    for (int i = 0; i < RT; i++) {
        int gr = row0 + ty * RT + i;
        if (gr < M) {
            float4 v = make_float4(acc[i][0], acc[i][1], acc[i][2], acc[i][3]);
            *reinterpret_cast<float4*>(&C[(size_t)gr * N + col0 + tx * 4]) = v;
        }
    }
}

// ---------------- per-node attention coefficients ----------------
__global__ __launch_bounds__(256) void k_alpha1(const float* __restrict__ h,
                                                const float* __restrict__ a_s, const float* __restrict__ a_d,
                                                float* __restrict__ asrc, float* __restrict__ adst, int n) {
    int node = blockIdx.x;
    int t = threadIdx.x, hd = t >> 6, lane = t & 63;
    float v = h[(size_t)node * 256 + t];
    float ps = v * a_s[t], pd = v * a_d[t];
    #pragma unroll
    for (int off = 32; off; off >>= 1) { ps += __shfl_xor(ps, off); pd += __shfl_xor(pd, off); }
    if (lane == 0) { asrc[node * 4 + hd] = ps; adst[node * 4 + hd] = pd; }
}

__global__ __launch_bounds__(256) void k_alpha2(const float* __restrict__ h,
                                                const float* __restrict__ a_s, const float* __restrict__ a_d,
                                                float* __restrict__ asrc, float* __restrict__ adst, int n) {
    int node = blockIdx.x * 4 + (threadIdx.x >> 6);
    int lane = threadIdx.x & 63;
    if (node >= n) return;
    float v = h[(size_t)node * 64 + lane];
    float ps = v * a_s[lane], pd = v * a_d[lane];
    #pragma unroll
    for (int off = 32; off; off >>= 1) { ps += __shfl_xor(ps, off); pd += __shfl_xor(pd, off); }
    if (lane == 0) { asrc[node] = ps; adst[node] = pd; }
}

// ---------------- attention aggregation, layer 1 ----------------
// block = node; wave = head; lane: q = l&15 (channel quad), rep = l>>4 (edge replica).
// 8 edges per iteration (2 float4 gathers per lane), no per-edge shuffles.
__global__ __launch_bounds__(256) void k_agg1(const float* __restrict__ h, const float* __restrict__ asrc,
                                              const float* __restrict__ adst, const int* __restrict__ rowptr,
                                              const int* __restrict__ col, const float* __restrict__ bias,
                                              float* __restrict__ out, int n) {
    int node = blockIdx.x;
    int t = threadIdx.x, hd = t >> 6, l = t & 63;
    int rep = l >> 4, q = l & 15;
    int base = rowptr[node], deg = rowptr[node + 1] - base;
    float adst_n = adst[node * 4 + hd];
    float e_self = leaky(asrc[node * 4 + hd] + adst_n);
    // max pass (lane-strided)
    float m = e_self;
    for (int i = l; i < deg; i += 64) {
        int s = col[base + i];
        m = fmaxf(m, leaky(asrc[s * 4 + hd] + adst_n));
    }
    #pragma unroll
    for (int off = 32; off; off >>= 1) m = fmaxf(m, __shfl_xor(m, off));

    float p_self = __expf(e_self - m);
    float4 acc = make_float4(0.f, 0.f, 0.f, 0.f);
    if (rep == 0) {
        float4 hv = *reinterpret_cast<const float4*>(&h[(size_t)node * 256 + hd * 64 + q * 4]);
        acc.x = p_self * hv.x; acc.y = p_self * hv.y; acc.z = p_self * hv.z; acc.w = p_self * hv.w;
    }
    float dsum = (l == 0) ? p_self : 0.f;

    for (int c0 = 0; c0 < deg; c0 += 8) {
        int ia = c0 + rep, ib = ia + 4;
        bool va = ia < deg, vb = ib < deg;
        int sa = 0, sb = 0;
        if (va) sa = col[base + ia];
        if (vb) sb = col[base + ib];
        float4 ha = make_float4(0.f, 0.f, 0.f, 0.f), hb = ha;
        if (va) ha = *reinterpret_cast<const float4*>(&h[(size_t)sa * 256 + hd * 64 + q * 4]);
        if (vb) hb = *reinterpret_cast<const float4*>(&h[(size_t)sb * 256 + hd * 64 + q * 4]);
        float pa = 0.f, pb = 0.f;
        if (va) pa = __expf(leaky(asrc[sa * 4 + hd] + adst_n) - m);
        if (vb) pb = __expf(leaky(asrc[sb * 4 + hd] + adst_n) - m);
        acc.x = fmaf(pa, ha.x, acc.x); acc.y = fmaf(pa, ha.y, acc.y);
        acc.z = fmaf(pa, ha.z, acc.z); acc.w = fmaf(pa, ha.w, acc.w);
        acc.x = fmaf(pb, hb.x, acc.x); acc.y = fmaf(pb, hb.y, acc.y);
        acc.z = fmaf(pb, hb.z, acc.z); acc.w = fmaf(pb, hb.w, acc.w);
        if (q == 0) dsum += pa + pb;
    }
    // reduce acc over replicas
    #pragma unroll
    for (int off = 16; off <= 32; off <<= 1) {
        acc.x += __shfl_xor(acc.x, off); acc.y += __shfl_xor(acc.y, off);
        acc.z += __shfl_xor(acc.z, off); acc.w += __shfl_xor(acc.w, off);
    }
    // reduce denom over all lanes
    #pragma unroll
    for (int off = 32; off; off >>= 1) dsum += __shfl_xor(dsum, off);
    if (rep == 0) {
        float inv = 1.f / (dsum + 1e-16f);
        float4 bv = *reinterpret_cast<const float4*>(&bias[hd * 64 + q * 4]);
        float4 r;
        r.x = fmaxf(acc.x * inv + bv.x, 0.f);
        r.y = fmaxf(acc.y * inv + bv.y, 0.f);
        r.z = fmaxf(acc.z * inv + bv.z, 0.f);
        r.w = fmaxf(acc.w * inv + bv.w, 0.f);
        *reinterpret_cast<float4*>(&out[(size_t)node * 256 + hd * 64 + q * 4]) = r;
    }
}

// ---------------- attention aggregation, layer 2 + fused FC ----------------
// wave = node (4 nodes/block); lane: q = l&15, rep = l>>4.
__global__ __launch_bounds__(256) void k_agg2fc(const float* __restrict__ h, const float* __restrict__ asrc,
                                                const float* __restrict__ adst, const int* __restrict__ rowptr,
                                                const int* __restrict__ col, const float* __restrict__ bias,
                                                const float* __restrict__ Wfc, const float* __restrict__ bfc,
                                                float* __restrict__ out, int n) {
    int node = blockIdx.x * 4 + (threadIdx.x >> 6);
    int l = threadIdx.x & 63;
    if (node >= n) return;
    int rep = l >> 4, q = l & 15;
    int base = rowptr[node], deg = rowptr[node + 1] - base;
    float adst_n = adst[node];
    float e_self = leaky(asrc[node] + adst_n);
    float m = e_self;
    for (int i = l; i < deg; i += 64) {
        int s = col[base + i];
        m = fmaxf(m, leaky(asrc[s] + adst_n));
    }
    #pragma unroll
    for (int off = 32; off; off >>= 1) m = fmaxf(m, __shfl_xor(m, off));

    float p_self = __expf(e_self - m);
    float4 acc = make_float4(0.f, 0.f, 0.f, 0.f);
    if (rep == 0) {
        float4 hv = *reinterpret_cast<const float4*>(&h[(size_t)node * 64 + q * 4]);
        acc.x = p_self * hv.x; acc.y = p_self * hv.y; acc.z = p_self * hv.z; acc.w = p_self * hv.w;
    }
    float dsum = (l == 0) ? p_self : 0.f;

    for (int c0 = 0; c0 < deg; c0 += 8) {
        int ia = c0 + rep, ib = ia + 4;
        bool va = ia < deg, vb = ib < deg;
        int sa = 0, sb = 0;
        if (va) sa = col[base + ia];
        if (vb) sb = col[base + ib];
        float4 ha = make_float4(0.f, 0.f, 0.f, 0.f), hb = ha;
        if (va) ha = *reinterpret_cast<const float4*>(&h[(size_t)sa * 64 + q * 4]);
        if (vb) hb = *reinterpret_cast<const float4*>(&h[(size_t)sb * 64 + q * 4]);
        float pa = 0.f, pb = 0.f;
        if (va) pa = __expf(leaky(asrc[sa] + adst_n) - m);
        if (vb) pb = __expf(leaky(asrc[sb] + adst_n) - m);
        acc.x = fmaf(pa, ha.x, acc.x); acc.y = fmaf(pa, ha.y, acc.y);
        acc.z = fmaf(pa, ha.z, acc.z); acc.w = fmaf(pa, ha.w, acc.w);
        acc.x = fmaf(pb, hb.x, acc.x); acc.y = fmaf(pb, hb.y, acc.y);
        acc.z = fmaf(pb, hb.z, acc.z); acc.w = fmaf(pb, hb.w, acc.w);
        if (q == 0) dsum += pa + pb;
    }
    #pragma unroll
    for (int off = 16; off <= 32; off <<= 1) {
        acc.x += __shfl_xor(acc.x, off); acc.y += __shfl_xor(acc.y, off);
        acc.z += __shfl_xor(acc.z, off); acc.w += __shfl_xor(acc.w, off);
    }
    #pragma unroll
    for (int off = 32; off; off >>= 1) dsum += __shfl_xor(dsum, off);
    float inv = 1.f / (dsum + 1e-16f);
    // r4: relu(acc/denom + bias) for channels q*4..q*4+3 (replicated across reps)
    float r0 = fmaxf(acc.x * inv + bias[q * 4 + 0], 0.f);
    float r1 = fmaxf(acc.y * inv + bias[q * 4 + 1], 0.f);
    float r2 = fmaxf(acc.z * inv + bias[q * 4 + 2], 0.f);
    float r3 = fmaxf(acc.w * inv + bias[q * 4 + 3], 0.f);
    // fused FC: out[node,a] = sum_ch r[ch]*Wfc[ch,a] + bfc[a]
    #pragma unroll
    for (int a = 0; a < 5; a++) {
        float part = r0 * Wfc[(q * 4 + 0) * 5 + a] + r1 * Wfc[(q * 4 + 1) * 5 + a]
                   + r2 * Wfc[(q * 4 + 2) * 5 + a] + r3 * Wfc[(q * 4 + 3) * 5 + a];
        #pragma unroll
        for (int off = 1; off <= 8; off <<= 1) part += __shfl_xor(part, off);
        if (l == 0) out[(size_t)node * 5 + a] = part + bfc[a];
    }
}

extern "C" void kernel_launch(void* const* d_in, const int* in_sizes, int n_in,
                              void* d_out, int out_size, void* d_ws, size_t ws_size,
                              hipStream_t stream) {
    const float* x   = (const float*)d_in[0];
    const int*   ei  = (const int*)d_in[1];
    const float* W1  = (const float*)d_in[2];
    const float* a1s = (const float*)d_in[3];
    const float* a1d = (const float*)d_in[4];
    const float* b1  = (const float*)d_in[5];
    const float* W2  = (const float*)d_in[6];
    const float* a2s = (const float*)d_in[7];
    const float* a2d = (const float*)d_in[8];
    const float* b2  = (const float*)d_in[9];
    const float* Wfc = (const float*)d_in[10];
    const float* bfc = (const float*)d_in[11];
    float* out = (float*)d_out;

    int n = in_sizes[0] / 128;
    int E = in_sizes[1] / 2;
    const int* srcn = ei;
    const int* dstn = ei + E;

    char* ws = (char*)d_ws;
    size_t off = 0;
    auto alloc = [&](size_t bytes) -> void* {
        void* p = ws + off;
        off += (bytes + 255) & ~(size_t)255;
        return p;
    };
    float* h1     = (float*)alloc((size_t)n * 256 * 4);
    float* out1   = (float*)alloc((size_t)n * 256 * 4);
    float* asrc1  = (float*)alloc((size_t)n * 4 * 4);
    float* adst1  = (float*)alloc((size_t)n * 4 * 4);
    int*   rowptr = (int*)alloc((size_t)(n + 1) * 4);
    int*   wptr   = (int*)alloc((size_t)n * 4);
    int*   col    = (int*)alloc((size_t)E * 4);
    int*   bsum   = (int*)alloc(64 * 4);
    int*   bscan  = (int*)alloc(64 * 4);
    // aliases for layer-2 (layer-1 versions dead by then)
    float* h2    = h1;
    float* asrc2 = asrc1;
    float* adst2 = adst1;

    int nb = (n + 1023) / 1024;

    // ---- CSR build (once; graph shared by both layers) ----
    hipMemsetAsync(wptr, 0, (size_t)n * 4, stream);
    k_count<<<(E + 255) / 256, 256, 0, stream>>>(dstn, E, wptr);
    k_scanA<<<nb, 256, 0, stream>>>(wptr, rowptr, bsum, n);
    k_scanB<<<1, 64, 0, stream>>>(bsum, bscan, nb);
    k_scanC<<<nb, 256, 0, stream>>>(rowptr, bscan, n);
    k_copy<<<(n + 255) / 256, 256, 0, stream>>>(rowptr, wptr, n);
    k_scatter<<<(E + 255) / 256, 256, 0, stream>>>(srcn, dstn, E, wptr, col);

    // ---- layer 1 ----
    k_gemm<128><<<dim3((n + 127) / 128, 4), 256, 0, stream>>>(x, W1, h1, n, 256, 128);
    k_alpha1<<<n, 256, 0, stream>>>(h1, a1s, a1d, asrc1, adst1, n);
    k_agg1<<<n, 256, 0, stream>>>(h1, asrc1, adst1, rowptr, col, b1, out1, n);
    // ---- layer 2 ----
    k_gemm<64><<<dim3((n + 63) / 64, 1), 256, 0, stream>>>(out1, W2, h2, n, 64, 256);
    k_alpha2<<<(n + 3) / 4, 256, 0, stream>>>(h2, a2s, a2d, asrc2, adst2, n);
    // ---- layer 2 aggregation + FC fused ----
    k_agg2fc<<<(n + 3) / 4, 256, 0, stream>>>(h2, asrc2, adst2, rowptr, col, b2, Wfc, bfc, out, n);
}

// Round 4
// 489.034 us; speedup vs baseline: 1.3741x; 1.1175x over previous
//
#include <hip/hip_runtime.h>

#define NEG_SLOPE 0.2f

__device__ __forceinline__ float leaky(float x) { return x > 0.f ? x : NEG_SLOPE * x; }

__device__ __forceinline__ void unpack2(unsigned u, float& lo, float& hi) {
    union { unsigned u; float f; } a, b;
    a.u = u << 16; b.u = u & 0xffff0000u;
    lo = a.f; hi = b.f;
}

__device__ __forceinline__ unsigned short f2bf(float f) {
    unsigned u = __float_as_uint(f);
    u += 0x7fffu + ((u >> 16) & 1u);
    return (unsigned short)(u >> 16);
}

// ---------------- CSR build (dst -> incoming srcs), shared by both layers ----------------
__global__ void k_count(const int* __restrict__ dst, int E, int* __restrict__ cnt) {
    int i = blockIdx.x * blockDim.x + threadIdx.x;
    if (i < E) atomicAdd(&cnt[dst[i]], 1);
}

__global__ __launch_bounds__(256) void k_scanA(const int* __restrict__ cnt, int* __restrict__ rowptr,
                                               int* __restrict__ bsum, int n) {
    int b = blockIdx.x, t = threadIdx.x;
    int lane = t & 63, w = t >> 6;
    int i0 = b * 1024 + t * 4;
    int v0 = (i0 + 0 < n) ? cnt[i0 + 0] : 0;
    int v1 = (i0 + 1 < n) ? cnt[i0 + 1] : 0;
    int v2 = (i0 + 2 < n) ? cnt[i0 + 2] : 0;
    int v3 = (i0 + 3 < n) ? cnt[i0 + 3] : 0;
    int r0 = v0, r1 = r0 + v1, r2 = r1 + v2, r3 = r2 + v3;
    int s = r3;
    int q = s;
    #pragma unroll
    for (int off = 1; off < 64; off <<= 1) {
        int tval = __shfl_up(q, off);
        if (lane >= off) q += tval;
    }
    __shared__ int wsum[4];
    if (lane == 63) wsum[w] = q;
    __syncthreads();
    int woff = 0;
    #pragma unroll
    for (int k = 0; k < 4; k++) if (k < w) woff += wsum[k];
    int excl = woff + q - s;
    if (i0 + 0 < n) rowptr[1 + i0 + 0] = excl + r0;
    if (i0 + 1 < n) rowptr[1 + i0 + 1] = excl + r1;
    if (i0 + 2 < n) rowptr[1 + i0 + 2] = excl + r2;
    if (i0 + 3 < n) rowptr[1 + i0 + 3] = excl + r3;
    if (t == 255) bsum[b] = woff + q;
}

__global__ void k_scanB(const int* __restrict__ bsum, int* __restrict__ bscan, int nb) {
    int lane = threadIdx.x & 63;
    int v = (lane < nb) ? bsum[lane] : 0;
    #pragma unroll
    for (int off = 1; off < 64; off <<= 1) {
        int t = __shfl_up(v, off);
        if (lane >= off) v += t;
    }
    if (lane < nb) bscan[lane] = v;
}

__global__ __launch_bounds__(256) void k_scanC(int* __restrict__ rowptr, const int* __restrict__ bscan, int n) {
    int b = blockIdx.x, t = threadIdx.x;
    int i0 = b * 1024 + t * 4;
    if (b == 0) {
        if (t == 0) rowptr[0] = 0;
        return;
    }
    int add = bscan[b - 1];
    #pragma unroll
    for (int j = 0; j < 4; j++)
        if (i0 + j < n) rowptr[1 + i0 + j] += add;
}

__global__ void k_copy(const int* __restrict__ src, int* __restrict__ dst, int n) {
    int i = blockIdx.x * blockDim.x + threadIdx.x;
    if (i < n) dst[i] = src[i];
}

__global__ void k_scatter(const int* __restrict__ srcn, const int* __restrict__ dstn, int E,
                          int* __restrict__ wptr, int* __restrict__ col) {
    int i = blockIdx.x * blockDim.x + threadIdx.x;
    if (i < E) {
        int d = dstn[i];
        int pos = atomicAdd(&wptr[d], 1);
        col[pos] = srcn[i];
    }
}

// ---------------- tiled fp32 GEMM with optional bf16 out + fused alpha ----------------
// C[M,N] = A[M,K] @ B[K,N]. BN=64, BK=32, 256 threads. A col-tile of 64 == one head's
// channel block, so asrc/adst are completed per-block -> plain store (no atomics).
template <int BMT, bool WF32, bool WBF16, bool FALPHA>
__global__ __launch_bounds__(256) void k_gemm(const float* __restrict__ A, const float* __restrict__ B,
                                              float* __restrict__ C, unsigned short* __restrict__ Cb,
                                              const float* __restrict__ a_s, const float* __restrict__ a_d,
                                              float* __restrict__ asrc, float* __restrict__ adst,
                                              int M, int N, int K) {
    constexpr int RT = BMT / 16;
    constexpr int APASS = BMT / 32;
    __shared__ float As[32][BMT + 4];
    __shared__ float Bs[32][68];
    int row0 = blockIdx.x * BMT, col0 = blockIdx.y * 64;
    int tid = threadIdx.x;
    int tx = tid & 15, ty = tid >> 4;
    float acc[RT][4] = {};
    for (int kk = 0; kk < K; kk += 32) {
        int ar = tid >> 3;
        int ac = (tid & 7) * 4;
        #pragma unroll
        for (int p = 0; p < APASS; p++) {
            int r = ar + p * 32;
            int gr = row0 + r;
            float4 v = make_float4(0.f, 0.f, 0.f, 0.f);
            if (gr < M) v = *reinterpret_cast<const float4*>(&A[(size_t)gr * K + kk + ac]);
            As[ac + 0][r] = v.x; As[ac + 1][r] = v.y;
            As[ac + 2][r] = v.z; As[ac + 3][r] = v.w;
        }
        int br = tid >> 4;
        int bc = (tid & 15) * 4;
        #pragma unroll
        for (int p = 0; p < 2; p++) {
            int r = br + p * 16;
            float4 v = *reinterpret_cast<const float4*>(&B[(size_t)(kk + r) * N + col0 + bc]);
            *reinterpret_cast<float4*>(&Bs[r][bc]) = v;
        }
        __syncthreads();
        #pragma unroll
        for (int k = 0; k < 32; k++) {
            float a[RT];
            #pragma unroll
            for (int i = 0; i < RT; i += 4) {
                float4 av = *reinterpret_cast<const float4*>(&As[k][ty * RT + i]);
                a[i + 0] = av.x; a[i + 1] = av.y; a[i + 2] = av.z; a[i + 3] = av.w;
            }
            float4 bv = *reinterpret_cast<const float4*>(&Bs[k][tx * 4]);
            float b[4] = {bv.x, bv.y, bv.z, bv.w};
            #pragma unroll
            for (int i = 0; i < RT; i++)
                #pragma unroll
                for (int j = 0; j < 4; j++) acc[i][j] = fmaf(a[i], b[j], acc[i][j]);
        }
        __syncthreads();
    }
    float4 as4, ad4;
    if (FALPHA) {
        as4 = *reinterpret_cast<const float4*>(&a_s[col0 + tx * 4]);
        ad4 = *reinterpret_cast<const float4*>(&a_d[col0 + tx * 4]);
    }
    int HV = N >> 6, hd = col0 >> 6;
    #pragma unroll
    for (int i = 0; i < RT; i++) {
        int gr = row0 + ty * RT + i;
        if (gr < M) {
            if (WF32) {
                float4 v = make_float4(acc[i][0], acc[i][1], acc[i][2], acc[i][3]);
                *reinterpret_cast<float4*>(&C[(size_t)gr * N + col0 + tx * 4]) = v;
            }
            if (WBF16) {
                ushort4 u;
                u.x = f2bf(acc[i][0]); u.y = f2bf(acc[i][1]);
                u.z = f2bf(acc[i][2]); u.w = f2bf(acc[i][3]);
                *reinterpret_cast<ushort4*>(&Cb[(size_t)gr * N + col0 + tx * 4]) = u;
            }
            if (FALPHA) {
                float ps = acc[i][0] * as4.x + acc[i][1] * as4.y + acc[i][2] * as4.z + acc[i][3] * as4.w;
                float pd = acc[i][0] * ad4.x + acc[i][1] * ad4.y + acc[i][2] * ad4.z + acc[i][3] * ad4.w;
                #pragma unroll
                for (int off = 1; off <= 8; off <<= 1) { ps += __shfl_xor(ps, off); pd += __shfl_xor(pd, off); }
                if (tx == 0) { asrc[(size_t)gr * HV + hd] = ps; adst[(size_t)gr * HV + hd] = pd; }
            }
        }
    }
}

// ---------------- attention aggregation, layer 1 (bf16 h gather) ----------------
// block = node; wave = head; lane: q = l&7 (8 channels via bf16x8), rep = l>>3 (8 edge reps).
__global__ __launch_bounds__(256) void k_agg1(const unsigned short* __restrict__ hb,
                                              const float* __restrict__ asrc, const float* __restrict__ adst,
                                              const int* __restrict__ rowptr, const int* __restrict__ col,
                                              const float* __restrict__ bias, float* __restrict__ out, int n) {
    int node = blockIdx.x;
    int t = threadIdx.x, hd = t >> 6, l = t & 63;
    int rep = l >> 3, q = l & 7;
    int base = rowptr[node], deg = rowptr[node + 1] - base;
    float adst_n = adst[node * 4 + hd];
    float e_self = leaky(asrc[node * 4 + hd] + adst_n);
    float m = e_self;
    for (int i = l; i < deg; i += 64) {
        int s = col[base + i];
        m = fmaxf(m, leaky(asrc[s * 4 + hd] + adst_n));
    }
    #pragma unroll
    for (int off = 32; off; off >>= 1) m = fmaxf(m, __shfl_xor(m, off));

    float p_self = __expf(e_self - m);
    float acc[8] = {};
    if (rep == 0) {
        uint4 u = *reinterpret_cast<const uint4*>(&hb[(size_t)node * 256 + hd * 64 + q * 8]);
        float f[8];
        unpack2(u.x, f[0], f[1]); unpack2(u.y, f[2], f[3]);
        unpack2(u.z, f[4], f[5]); unpack2(u.w, f[6], f[7]);
        #pragma unroll
        for (int j = 0; j < 8; j++) acc[j] = p_self * f[j];
    }
    float dsum = (l == 0) ? p_self : 0.f;

    for (int c0 = 0; c0 < deg; c0 += 16) {
        int ia = c0 + rep, ib = ia + 8;
        bool va = ia < deg, vb = ib < deg;
        int sa = 0, sb = 0;
        if (va) sa = col[base + ia];
        if (vb) sb = col[base + ib];
        uint4 ua = make_uint4(0, 0, 0, 0), ub = make_uint4(0, 0, 0, 0);
        if (va) ua = *reinterpret_cast<const uint4*>(&hb[(size_t)sa * 256 + hd * 64 + q * 8]);
        if (vb) ub = *reinterpret_cast<const uint4*>(&hb[(size_t)sb * 256 + hd * 64 + q * 8]);
        float pa = 0.f, pb = 0.f;
        if (va) pa = __expf(leaky(asrc[sa * 4 + hd] + adst_n) - m);
        if (vb) pb = __expf(leaky(asrc[sb * 4 + hd] + adst_n) - m);
        float f[8];
        unpack2(ua.x, f[0], f[1]); unpack2(ua.y, f[2], f[3]);
        unpack2(ua.z, f[4], f[5]); unpack2(ua.w, f[6], f[7]);
        #pragma unroll
        for (int j = 0; j < 8; j++) acc[j] = fmaf(pa, f[j], acc[j]);
        unpack2(ub.x, f[0], f[1]); unpack2(ub.y, f[2], f[3]);
        unpack2(ub.z, f[4], f[5]); unpack2(ub.w, f[6], f[7]);
        #pragma unroll
        for (int j = 0; j < 8; j++) acc[j] = fmaf(pb, f[j], acc[j]);
        if (q == 0) dsum += pa + pb;
    }
    // reduce acc over the 8 replicas (lane bits 3,4,5)
    #pragma unroll
    for (int off = 8; off <= 32; off <<= 1)
        #pragma unroll
        for (int j = 0; j < 8; j++) acc[j] += __shfl_xor(acc[j], off);
    #pragma unroll
    for (int off = 32; off; off >>= 1) dsum += __shfl_xor(dsum, off);
    if (rep == 0) {
        float inv = 1.f / (dsum + 1e-16f);
        float r[8];
        #pragma unroll
        for (int j = 0; j < 8; j++) r[j] = fmaxf(acc[j] * inv + bias[hd * 64 + q * 8 + j], 0.f);
        float4 v0 = make_float4(r[0], r[1], r[2], r[3]);
        float4 v1 = make_float4(r[4], r[5], r[6], r[7]);
        *reinterpret_cast<float4*>(&out[(size_t)node * 256 + hd * 64 + q * 8]) = v0;
        *reinterpret_cast<float4*>(&out[(size_t)node * 256 + hd * 64 + q * 8 + 4]) = v1;
    }
}

// ---------------- attention aggregation, layer 2 + fused FC (fp32 gather) ----------------
__global__ __launch_bounds__(256) void k_agg2fc(const float* __restrict__ h, const float* __restrict__ asrc,
                                                const float* __restrict__ adst, const int* __restrict__ rowptr,
                                                const int* __restrict__ col, const float* __restrict__ bias,
                                                const float* __restrict__ Wfc, const float* __restrict__ bfc,
                                                float* __restrict__ out, int n) {
    int node = blockIdx.x * 4 + (threadIdx.x >> 6);
    int l = threadIdx.x & 63;
    if (node >= n) return;
    int rep = l >> 4, q = l & 15;
    int base = rowptr[node], deg = rowptr[node + 1] - base;
    float adst_n = adst[node];
    float e_self = leaky(asrc[node] + adst_n);
    float m = e_self;
    for (int i = l; i < deg; i += 64) {
        int s = col[base + i];
        m = fmaxf(m, leaky(asrc[s] + adst_n));
    }
    #pragma unroll
    for (int off = 32; off; off >>= 1) m = fmaxf(m, __shfl_xor(m, off));

    float p_self = __expf(e_self - m);
    float4 acc = make_float4(0.f, 0.f, 0.f, 0.f);
    if (rep == 0) {
        float4 hv = *reinterpret_cast<const float4*>(&h[(size_t)node * 64 + q * 4]);
        acc.x = p_self * hv.x; acc.y = p_self * hv.y; acc.z = p_self * hv.z; acc.w = p_self * hv.w;
    }
    float dsum = (l == 0) ? p_self : 0.f;

    for (int c0 = 0; c0 < deg; c0 += 8) {
        int ia = c0 + rep, ib = ia + 4;
        bool va = ia < deg, vb = ib < deg;
        int sa = 0, sb = 0;
        if (va) sa = col[base + ia];
        if (vb) sb = col[base + ib];
        float4 ha = make_float4(0.f, 0.f, 0.f, 0.f), hbv = ha;
        if (va) ha = *reinterpret_cast<const float4*>(&h[(size_t)sa * 64 + q * 4]);
        if (vb) hbv = *reinterpret_cast<const float4*>(&h[(size_t)sb * 64 + q * 4]);
        float pa = 0.f, pb = 0.f;
        if (va) pa = __expf(leaky(asrc[sa] + adst_n) - m);
        if (vb) pb = __expf(leaky(asrc[sb] + adst_n) - m);
        acc.x = fmaf(pa, ha.x, acc.x); acc.y = fmaf(pa, ha.y, acc.y);
        acc.z = fmaf(pa, ha.z, acc.z); acc.w = fmaf(pa, ha.w, acc.w);
        acc.x = fmaf(pb, hbv.x, acc.x); acc.y = fmaf(pb, hbv.y, acc.y);
        acc.z = fmaf(pb, hbv.z, acc.z); acc.w = fmaf(pb, hbv.w, acc.w);
        if (q == 0) dsum += pa + pb;
    }
    #pragma unroll
    for (int off = 16; off <= 32; off <<= 1) {
        acc.x += __shfl_xor(acc.x, off); acc.y += __shfl_xor(acc.y, off);
        acc.z += __shfl_xor(acc.z, off); acc.w += __shfl_xor(acc.w, off);
    }
    #pragma unroll
    for (int off = 32; off; off >>= 1) dsum += __shfl_xor(dsum, off);
    float inv = 1.f / (dsum + 1e-16f);
    float r0 = fmaxf(acc.x * inv + bias[q * 4 + 0], 0.f);
    float r1 = fmaxf(acc.y * inv + bias[q * 4 + 1], 0.f);
    float r2 = fmaxf(acc.z * inv + bias[q * 4 + 2], 0.f);
    float r3 = fmaxf(acc.w * inv + bias[q * 4 + 3], 0.f);
    #pragma unroll
    for (int a = 0; a < 5; a++) {
        float part = r0 * Wfc[(q * 4 + 0) * 5 + a] + r1 * Wfc[(q * 4 + 1) * 5 + a]
                   + r2 * Wfc[(q * 4 + 2) * 5 + a] + r3 * Wfc[(q * 4 + 3) * 5 + a];
        #pragma unroll
        for (int off = 1; off <= 8; off <<= 1) part += __shfl_xor(part, off);
        if (l == 0) out[(size_t)node * 5 + a] = part + bfc[a];
    }
}

extern "C" void kernel_launch(void* const* d_in, const int* in_sizes, int n_in,
                              void* d_out, int out_size, void* d_ws, size_t ws_size,
                              hipStream_t stream) {
    const float* x   = (const float*)d_in[0];
    const int*   ei  = (const int*)d_in[1];
    const float* W1  = (const float*)d_in[2];
    const float* a1s = (const float*)d_in[3];
    const float* a1d = (const float*)d_in[4];
    const float* b1  = (const float*)d_in[5];
    const float* W2  = (const float*)d_in[6];
    const float* a2s = (const float*)d_in[7];
    const float* a2d = (const float*)d_in[8];
    const float* b2  = (const float*)d_in[9];
    const float* Wfc = (const float*)d_in[10];
    const float* bfc = (const float*)d_in[11];
    float* out = (float*)d_out;

    int n = in_sizes[0] / 128;
    int E = in_sizes[1] / 2;
    const int* srcn = ei;
    const int* dstn = ei + E;

    char* ws = (char*)d_ws;
    size_t off = 0;
    auto alloc = [&](size_t bytes) -> void* {
        void* p = ws + off;
        off += (bytes + 255) & ~(size_t)255;
        return p;
    };
    unsigned short* h1b = (unsigned short*)alloc((size_t)n * 256 * 2);
    float* out1   = (float*)alloc((size_t)n * 256 * 4);
    float* h2     = (float*)alloc((size_t)n * 64 * 4);
    float* asrc1  = (float*)alloc((size_t)n * 4 * 4);
    float* adst1  = (float*)alloc((size_t)n * 4 * 4);
    int*   rowptr = (int*)alloc((size_t)(n + 1) * 4);
    int*   wptr   = (int*)alloc((size_t)n * 4);
    int*   col    = (int*)alloc((size_t)E * 4);
    int*   bsum   = (int*)alloc(64 * 4);
    int*   bscan  = (int*)alloc(64 * 4);
    float* asrc2 = asrc1;  // layer-1 versions dead before gemm2 writes these
    float* adst2 = adst1;

    int nb = (n + 1023) / 1024;

    // ---- CSR build (once; graph shared by both layers) ----
    hipMemsetAsync(wptr, 0, (size_t)n * 4, stream);
    k_count<<<(E + 255) / 256, 256, 0, stream>>>(dstn, E, wptr);
    k_scanA<<<nb, 256, 0, stream>>>(wptr, rowptr, bsum, n);
    k_scanB<<<1, 64, 0, stream>>>(bsum, bscan, nb);
    k_scanC<<<nb, 256, 0, stream>>>(rowptr, bscan, n);
    k_copy<<<(n + 255) / 256, 256, 0, stream>>>(rowptr, wptr, n);
    k_scatter<<<(E + 255) / 256, 256, 0, stream>>>(srcn, dstn, E, wptr, col);

    // ---- layer 1: GEMM (bf16 out + fused alpha), then aggregation ----
    k_gemm<128, false, true, true><<<dim3((n + 127) / 128, 4), 256, 0, stream>>>(
        x, W1, nullptr, h1b, a1s, a1d, asrc1, adst1, n, 256, 128);
    k_agg1<<<n, 256, 0, stream>>>(h1b, asrc1, adst1, rowptr, col, b1, out1, n);
    // ---- layer 2: GEMM (fp32 out + fused alpha), aggregation + FC fused ----
    k_gemm<64, true, false, true><<<dim3((n + 63) / 64, 1), 256, 0, stream>>>(
        out1, W2, h2, nullptr, a2s, a2d, asrc2, adst2, n, 64, 256);
    k_agg2fc<<<(n + 3) / 4, 256, 0, stream>>>(h2, asrc2, adst2, rowptr, col, b2, Wfc, bfc, out, n);
}